// Round 3
// baseline (75.060 us; speedup 1.0000x reference)
//
#include <hip/hip_runtime.h>
#include <math.h>

// Problem constants (fixed by setup_inputs): bs=16, Q=300, C=2, P=320
#define BS 16
#define QN 300
#define CN 2
#define PN 320
#define NN (BS * QN)   // 4800 query rows
#define KPRED 53
#define KTGT 54
#define TILE_N 4       // query rows per block -> 1200 blocks
#define STAGE_N (TILE_N * KPRED + TILE_N * CN)   // 220 staged floats

// thread = target p (0..319, 5 waves/block); block handles TILE_N query rows.
// Pred rows are staged into LDS with ONE coalesced global burst (4 rows of
// pred_kpts are contiguous in memory), then read back as broadcast ds_reads
// (same address across all lanes -> conflict-free). Target features live in
// registers; vis converted to float ONCE per block (vjf), not per row.
// VGPR budget: tx18+ty18+vjf18+w17=71 + ~25 temps -> aim <=102 (5 waves/SIMD).
__global__ __launch_bounds__(PN) void hungarian_cost_kernel(
    const float* __restrict__ pred_logits,  // [N, 2]
    const float* __restrict__ pred_kpts,    // [N, 53]
    const float* __restrict__ tgt_kpts,     // [P, 54]
    const int*   __restrict__ tgt_ids,      // [P]
    float* __restrict__ out)                // [N, P]
{
    __shared__ float sk[STAGE_N];
    const int p  = threadIdx.x;
    const int n0 = blockIdx.x * TILE_N;

    // ---- coalesced staging: 212 contiguous pred_kpts floats + 8 logits ----
    if (p < STAGE_N) {
        sk[p] = (p < TILE_N * KPRED)
                    ? pred_kpts[(size_t)n0 * KPRED + p]
                    : pred_logits[n0 * CN + (p - TILE_N * KPRED)];
    }

    // ---- per-thread target features (registers) ----
    float tx[18], ty[18], vjf[18], w[17];
    {
        const float* t = tgt_kpts + (size_t)p * KTGT;
        #pragma unroll
        for (int j = 0; j < 18; ++j) {
            tx[j] = t[3 * j];
            ty[j] = t[3 * j + 1];
            const float vv = t[3 * j + 2];
            vjf[j] = (vv == 1.0f) ? 1.0f : 0.0f;
            if (j >= 1) w[j - 1] = vv;   // tgt kpts-class vec aliases vis slots
        }
    }
    const int cls = tgt_ids[p];

    __syncthreads();

    #pragma unroll
    for (int ni = 0; ni < TILE_N; ++ni) {
        const int n = n0 + ni;
        const float* k = &sk[ni * KPRED];   // broadcast LDS reads

        const float dx0 = k[0] - tx[0];
        const float dy0 = k[1] - ty[0];

        float cd = 0.0f;   // cost_deltas (L1 on relative coords)
        float ck = 0.0f;   // cost_kpts:  xa - txa = 2*dx + dx0
        float cq = 0.0f;   // kpts-class squared L2
        #pragma unroll
        for (int j = 1; j < 18; ++j) {
            const float dx = k[3 * j - 1] - tx[j];
            const float dy = k[3 * j]     - ty[j];
            cd = fmaf(vjf[j], fabsf(dx) + fabsf(dy), cd);
            const float ax = fmaf(2.0f, dx, dx0);
            const float ay = fmaf(2.0f, dy, dy0);
            ck = fmaf(vjf[j], fabsf(ax) + fabsf(ay), ck);
            const float d = k[3 * j + 1] - w[j - 1];
            cq = fmaf(d, d, cq);
        }

        // cost_ctrs = vis0 * ||(dx0, dy0)||
        const float cc = vjf[0] * sqrtf(fmaf(dx0, dx0, dy0 * dy0));

        // cost_class = -softmax(logits)[cls]
        const float l0 = sk[TILE_N * KPRED + 2 * ni];
        const float l1 = sk[TILE_N * KPRED + 2 * ni + 1];
        const float m  = fmaxf(l0, l1);
        const float e0 = __expf(l0 - m);
        const float e1 = __expf(l1 - m);
        const float inv = 1.0f / (e0 + e1);
        const float ccls = -((cls == 0) ? e0 : e1) * inv;

        out[(size_t)n * PN + p] = ck + cc + cd + ccls + sqrtf(cq);
    }
}

extern "C" void kernel_launch(void* const* d_in, const int* in_sizes, int n_in,
                              void* d_out, int out_size, void* d_ws, size_t ws_size,
                              hipStream_t stream) {
    const float* pred_logits = (const float*)d_in[0];
    const float* pred_kpts   = (const float*)d_in[1];
    const float* tgt_kpts    = (const float*)d_in[2];
    const int*   tgt_ids     = (const int*)d_in[3];
    float* out = (float*)d_out;

    dim3 grid(NN / TILE_N);   // 1200 blocks
    dim3 block(PN);           // 320 threads = 5 waves
    hipLaunchKernelGGL(hungarian_cost_kernel, grid, block, 0, stream,
                       pred_logits, pred_kpts, tgt_kpts, tgt_ids, out);
}